// Round 1
// baseline (586.131 us; speedup 1.0000x reference)
//
#include <hip/hip_runtime.h>

// Dims from the reference
#define B_  4
#define N_  4
#define D_  41
#define H_  16
#define W_  44
#define C_  80
#define NX_ 200
#define NY_ 200
#define NPTS   (B_*N_*D_*H_*W_)   // 461824
#define PER_B  (N_*D_*H_*W_)      // 115456
#define PLANE  (NX_*NY_)          // 40000

// Kernel A: per-point voxel offset (or -1 if culled).
// Exactly mirrors JAX: idx = trunc((geom - (bx - dx/2)) / dx)
//   bx - dx/2 = (-50, -50, -10); dx = (0.5, 0.5, 20)
__global__ void compute_offsets(const float* __restrict__ geom,
                                const int*   __restrict__ mask,
                                int*         __restrict__ offs) {
    int p = blockIdx.x * blockDim.x + threadIdx.x;
    if (p >= NPTS) return;
    float fx = geom[3*p + 0];
    float fy = geom[3*p + 1];
    float fz = geom[3*p + 2];
    int gx = (int)((fx + 50.0f) / 0.5f);   // same IEEE ops as JAX, trunc-toward-zero
    int gy = (int)((fy + 50.0f) / 0.5f);
    int gz = (int)((fz + 10.0f) / 20.0f);
    bool kept = (gx >= 0) & (gx < NX_) & (gy >= 0) & (gy < NY_)
              & (gz >= 0) & (gz < 1) & (mask[p] != 0);
    int b = p / PER_B;
    // out[((b*C + c)*NX + gx)*NY + gy]; channel term added in scatter kernel
    offs[p] = kept ? (b * (C_ * PLANE) + gx * NY_ + gy) : -1;
}

// Kernel B: one thread per (point, channel). x reads coalesced; scattered
// predicated atomicAdd into the final (B,C,NX,NY) layout with the /4 folded in.
__global__ void scatter_add(const float* __restrict__ x,
                            const int*   __restrict__ offs,
                            float*       __restrict__ out) {
    int gid = blockIdx.x * blockDim.x + threadIdx.x;
    if (gid >= NPTS * C_) return;           // 36,945,920 < 2^31
    int p = gid / C_;
    int c = gid - p * C_;
    int off = offs[p];
    if (off >= 0) {
        atomicAdd(out + off + c * PLANE, x[gid] * 0.25f);
    }
}

extern "C" void kernel_launch(void* const* d_in, const int* in_sizes, int n_in,
                              void* d_out, int out_size, void* d_ws, size_t ws_size,
                              hipStream_t stream) {
    const float* geom = (const float*)d_in[0];
    const int*   mask = (const int*)  d_in[1];   // bool in ref; harness passes integers as int32
    const float* x    = (const float*)d_in[2];
    float*       out  = (float*)d_out;
    int*         offs = (int*)d_ws;              // NPTS * 4 B = 1.85 MB scratch

    hipMemsetAsync(d_out, 0, (size_t)out_size * sizeof(float), stream);

    compute_offsets<<<(NPTS + 255) / 256, 256, 0, stream>>>(geom, mask, offs);

    const int total = NPTS * C_;
    scatter_add<<<(total + 255) / 256, 256, 0, stream>>>(x, offs, out);
}

// Round 2
// 125.901 us; speedup vs baseline: 4.6555x; 4.6555x over previous
//
#include <hip/hip_runtime.h>

// Dims from the reference
#define B_  4
#define N_  4
#define D_  41
#define H_  16
#define W_  44
#define C_  80
#define NX_ 200
#define NY_ 200
#define NPTS   (B_*N_*D_*H_*W_)   // 461824
#define PER_B  (N_*D_*H_*W_)      // 115456
#define PLANE  (NX_*NY_)          // 40000
#define NVOX   (B_*PLANE)         // 160000
#define SCAN_BLK 1024
#define NSCANB ((NVOX + SCAN_BLK - 1) / SCAN_BLK)   // 157

// ---------------------------------------------------------------------------
// K1: per-point voxel id (-1 if culled) + per-voxel count.
// Binning mirrors JAX bit-exactly: idx = trunc((geom - (bx - dx/2)) / dx)
//   bx - dx/2 = (-50, -50, -10); dx = (0.5, 0.5, 20)
__global__ void bin_count(const float* __restrict__ geom,
                          const int*   __restrict__ mask,
                          int*         __restrict__ voxid,
                          int*         __restrict__ cnt) {
    int p = blockIdx.x * blockDim.x + threadIdx.x;
    if (p >= NPTS) return;
    float fx = geom[3*p + 0];
    float fy = geom[3*p + 1];
    float fz = geom[3*p + 2];
    int gx = (int)((fx + 50.0f) / 0.5f);   // trunc-toward-zero == astype(int32)
    int gy = (int)((fy + 50.0f) / 0.5f);
    int gz = (int)((fz + 10.0f) / 20.0f);
    bool kept = (gx >= 0) & (gx < NX_) & (gy >= 0) & (gy < NY_)
              & (gz >= 0) & (gz < 1) & (mask[p] != 0);
    int b = p / PER_B;
    int v = kept ? (b * PLANE + gx * NY_ + gy) : -1;
    voxid[p] = v;
    if (v >= 0) atomicAdd(&cnt[v], 1);
}

// ---------------------------------------------------------------------------
// Exclusive scan of cnt[NVOX] -> start[NVOX], three tiny kernels.
__global__ void scan1(const int* __restrict__ cnt,
                      int* __restrict__ start,
                      int* __restrict__ bsum) {
    __shared__ int sh[SCAN_BLK];
    int i = blockIdx.x * SCAN_BLK + threadIdx.x;
    int v = (i < NVOX) ? cnt[i] : 0;
    sh[threadIdx.x] = v;
    __syncthreads();
    int val = v;                            // Hillis-Steele inclusive scan
    for (int off = 1; off < SCAN_BLK; off <<= 1) {
        int t = (threadIdx.x >= (unsigned)off) ? sh[threadIdx.x - off] : 0;
        __syncthreads();
        val += t;
        sh[threadIdx.x] = val;
        __syncthreads();
    }
    if (i < NVOX) start[i] = val - v;       // exclusive within block
    if (threadIdx.x == SCAN_BLK - 1) bsum[blockIdx.x] = val;
}

__global__ void scan2(int* __restrict__ bsum) {
    if (blockIdx.x == 0 && threadIdx.x == 0) {   // 157 values: serial is fine
        int acc = 0;
        for (int i = 0; i < NSCANB; ++i) { int t = bsum[i]; bsum[i] = acc; acc += t; }
    }
}

__global__ void scan3(int* __restrict__ start,
                      const int* __restrict__ bsum,
                      int* __restrict__ cursor) {
    int i = blockIdx.x * SCAN_BLK + threadIdx.x;
    if (i < NVOX) {
        int s = start[i] + bsum[blockIdx.x];
        start[i]  = s;
        cursor[i] = s;
    }
}

// ---------------------------------------------------------------------------
// K3: place point indices into per-voxel lists.
__global__ void place(const int* __restrict__ voxid,
                      int* __restrict__ cursor,
                      int* __restrict__ plist) {
    int p = blockIdx.x * blockDim.x + threadIdx.x;
    if (p >= NPTS) return;
    int v = voxid[p];
    if (v >= 0) {
        int pos = atomicAdd(&cursor[v], 1);
        plist[pos] = p;
    }
}

// ---------------------------------------------------------------------------
// K4: gather — one thread per (voxel, channel). Sums its point list, writes
// once (no atomics, no output memset needed). Lanes = consecutive channels of
// one voxel -> x reads coalesced; writes stride PLANE but adjacent waves fill
// adjacent gy of the same cache line -> L2 coalesces the writeback.
__global__ void gather(const float* __restrict__ x,
                       const int*   __restrict__ start,
                       const int*   __restrict__ cnt,
                       const int*   __restrict__ plist,
                       float*       __restrict__ out) {
    int gid = blockIdx.x * blockDim.x + threadIdx.x;
    if (gid >= NVOX * C_) return;           // 12.8M
    int v = gid / C_;
    int c = gid - v * C_;
    int s = start[v];
    int n = cnt[v];
    float sum = 0.0f;
    for (int i = 0; i < n; ++i) {
        int p = plist[s + i];
        sum += x[p * C_ + c];
    }
    int b  = v / PLANE;
    int pl = v - b * PLANE;
    out[(b * C_ + c) * PLANE + pl] = sum * 0.25f;
}

// ---------------------------------------------------------------------------
// Fallback (Round-1 atomic path) if ws_size is too small for CSR buffers.
__global__ void compute_offsets_fb(const float* __restrict__ geom,
                                   const int*   __restrict__ mask,
                                   int*         __restrict__ offs) {
    int p = blockIdx.x * blockDim.x + threadIdx.x;
    if (p >= NPTS) return;
    float fx = geom[3*p], fy = geom[3*p+1], fz = geom[3*p+2];
    int gx = (int)((fx + 50.0f) / 0.5f);
    int gy = (int)((fy + 50.0f) / 0.5f);
    int gz = (int)((fz + 10.0f) / 20.0f);
    bool kept = (gx >= 0) & (gx < NX_) & (gy >= 0) & (gy < NY_)
              & (gz >= 0) & (gz < 1) & (mask[p] != 0);
    int b = p / PER_B;
    offs[p] = kept ? (b * (C_ * PLANE) + gx * NY_ + gy) : -1;
}

__global__ void scatter_add_fb(const float* __restrict__ x,
                               const int*   __restrict__ offs,
                               float*       __restrict__ out) {
    int gid = blockIdx.x * blockDim.x + threadIdx.x;
    if (gid >= NPTS * C_) return;
    int p = gid / C_;
    int c = gid - p * C_;
    int off = offs[p];
    if (off >= 0) atomicAdd(out + off + c * PLANE, x[gid] * 0.25f);
}

// ---------------------------------------------------------------------------
extern "C" void kernel_launch(void* const* d_in, const int* in_sizes, int n_in,
                              void* d_out, int out_size, void* d_ws, size_t ws_size,
                              hipStream_t stream) {
    const float* geom = (const float*)d_in[0];
    const int*   mask = (const int*)  d_in[1];
    const float* x    = (const float*)d_in[2];
    float*       out  = (float*)d_out;

    // Workspace layout (ints): voxid[NPTS] cnt[NVOX] start[NVOX] cursor[NVOX]
    //                          bsum[256] plist[NPTS]
    const size_t need = ((size_t)NPTS * 2 + (size_t)NVOX * 3 + 256) * sizeof(int);
    if (ws_size < need) {
        // fallback: Round-1 atomic scatter
        int* offs = (int*)d_ws;
        hipMemsetAsync(d_out, 0, (size_t)out_size * sizeof(float), stream);
        compute_offsets_fb<<<(NPTS + 255) / 256, 256, 0, stream>>>(geom, mask, offs);
        const int total = NPTS * C_;
        scatter_add_fb<<<(total + 255) / 256, 256, 0, stream>>>(x, offs, out);
        return;
    }

    int* voxid  = (int*)d_ws;
    int* cnt    = voxid + NPTS;
    int* start  = cnt + NVOX;
    int* cursor = start + NVOX;
    int* bsum   = cursor + NVOX;
    int* plist  = bsum + 256;

    hipMemsetAsync(cnt, 0, (size_t)NVOX * sizeof(int), stream);

    bin_count<<<(NPTS + 255) / 256, 256, 0, stream>>>(geom, mask, voxid, cnt);
    scan1<<<NSCANB, SCAN_BLK, 0, stream>>>(cnt, start, bsum);
    scan2<<<1, 64, 0, stream>>>(bsum);
    scan3<<<NSCANB, SCAN_BLK, 0, stream>>>(start, bsum, cursor);
    place<<<(NPTS + 255) / 256, 256, 0, stream>>>(voxid, cursor, plist);

    const int gtotal = NVOX * C_;
    gather<<<(gtotal + 255) / 256, 256, 0, stream>>>(x, start, cnt, plist, out);
}